// Round 2
// baseline (2386.522 us; speedup 1.0000x reference)
//
#include <hip/hip_runtime.h>
#include <hip/hip_bf16.h>
#include <math.h>

// ---------------- constants ----------------
#define Bb 32
#define Ss 512
#define Nn 32
#define DTt 64
#define Dd 128
#define Ee 16
#define HEe 256
#define MOo 128

__device__ inline float waveReduceSum(float v){
  #pragma unroll
  for (int off = 32; off > 0; off >>= 1) v += __shfl_xor(v, off, 64);
  return v;
}

// ---------------- transpose TCN weights: w[layer][co][ci][k] -> wt[layer][k][ci][co] ----------------
__global__ void transpose_w_kernel(const float* __restrict__ w1, const float* __restrict__ w2,
                                   float* __restrict__ wt1, float* __restrict__ wt2){
  int idx = blockIdx.x * 256 + threadIdx.x;
  if (idx >= 4*64*64*3) return;
  int k = idx % 3;
  int ci = (idx/3) & 63;
  int co = (idx/192) & 63;
  int layer = idx / 12288;
  int dst = layer*12288 + k*4096 + ci*64 + co;
  wt1[dst] = w1[idx];
  wt2[dst] = w2[idx];
}

// ---------------- proj + positional encoding; h layout (bn_local, c, t) ----------------
__global__ void proj_pe_kernel(const float* __restrict__ x, const float* __restrict__ pw,
                               const float* __restrict__ pb, float* __restrict__ h, int chunk_base){
  int idx = blockIdx.x * 256 + threadIdx.x;
  int t = idx & 511;
  int c = (idx >> 9) & 63;
  int bnl = idx >> 15;
  int bn = chunk_base + bnl;
  int b = bn >> 5, n = bn & 31;
  float xv = x[(size_t)b*(Ss*Nn) + (size_t)t*Nn + n];
  // div = exp(-(ln 10000)/64 * (c & ~1))
  float ang = (float)t * expf(-0.14391156831f * (float)(c & ~1));
  float pe = (c & 1) ? cosf(ang) : sinf(ang);
  h[idx] = fmaf(xv, pw[c], pb[c]) + pe;
}

// ---------------- TCN causal dilated conv: out[co,t] = act(sum_{k,ci} wt[k][ci][co]*in[ci,t-(2-k)*dil] + b) ----------------
// if res != null:  out = relu( relu(conv+b) + res )   (res may alias out; per-thread same-element RMW)
__global__ __launch_bounds__(256) void tcn_conv_kernel(
    const float* __restrict__ in, float* __restrict__ out, const float* __restrict__ res,
    const float* __restrict__ wt, const float* __restrict__ bias, int dil){
  int t = blockIdx.x * 256 + threadIdx.x;
  int bn = blockIdx.y;
  const float* inb = in + (size_t)bn * (64*512);
  float acc[64];
  #pragma unroll
  for (int co = 0; co < 64; ++co) acc[co] = 0.f;
  #pragma unroll
  for (int k = 0; k < 3; ++k){
    int st = t - (2-k)*dil;
    if (st < 0) continue;
    const float* wk = wt + k*4096;
    for (int ci = 0; ci < 64; ++ci){
      float v = inb[ci*512 + st];
      const float* wp = wk + ci*64;   // uniform address -> scalar loads
      #pragma unroll
      for (int co = 0; co < 64; ++co) acc[co] = fmaf(v, wp[co], acc[co]);
    }
  }
  float* outb = out + (size_t)bn * (64*512);
  const float* resb = res ? res + (size_t)bn * (64*512) : nullptr;
  #pragma unroll
  for (int co = 0; co < 64; ++co){
    float a = fmaxf(acc[co] + bias[co], 0.f);
    if (resb) a = fmaxf(a + resb[co*512 + t], 0.f);
    outb[co*512 + t] = a;
  }
}

// ---------------- post-TCN layernorm (over c) + masked mean-pool over t + last-t extract ----------------
__global__ __launch_bounds__(256) void ln_pool_kernel(
    const float* __restrict__ h, const float* __restrict__ g, const float* __restrict__ bta,
    const float* __restrict__ mask, float* __restrict__ pooled, float* __restrict__ st_last,
    int chunk_base){
  __shared__ float tile[64][65];
  int bnl = blockIdx.x;
  int bn = chunk_base + bnl;
  int tid = threadIdx.x;
  const float* hb = h + (size_t)bnl * (64*512);
  float pool_acc = 0.f, last_val = 0.f;
  for (int ti2 = 0; ti2 < 8; ++ti2){
    int t0 = ti2 * 64;
    #pragma unroll
    for (int r = 0; r < 16; ++r){
      int lin = r*256 + tid;
      int c = lin >> 6, tt = lin & 63;
      tile[c][tt] = hb[c*512 + t0 + tt];
    }
    __syncthreads();
    if (tid < 64){
      float m = 0.f;
      for (int c = 0; c < 64; ++c) m += tile[c][tid];
      m *= (1.f/64.f);
      float var = 0.f;
      for (int c = 0; c < 64; ++c){ float d = tile[c][tid] - m; var += d*d; }
      var *= (1.f/64.f);
      float rstd = rsqrtf(var + 1e-5f);
      for (int c = 0; c < 64; ++c) tile[c][tid] = (tile[c][tid]-m)*rstd*g[c] + bta[c];
    }
    __syncthreads();
    if (tid < 64){
      float s = 0.f;
      for (int tt = 0; tt < 64; ++tt) s += tile[tid][tt];
      pool_acc += s;
      if (ti2 == 7) last_val = tile[tid][63];
    }
    __syncthreads();
  }
  if (tid < 64){
    float mk = mask[bn];
    pooled[(size_t)bn*64 + tid]  = pool_acc * (1.f/512.f) * mk;
    st_last[(size_t)bn*64 + tid] = last_val * mk;
  }
}

// ---------------- z init: z = pooled @ pool_w + pool_b + pos_inter[n] ----------------
__global__ void z_init_kernel(const float* __restrict__ pooled, const float* __restrict__ pw,
                              const float* __restrict__ pb, const float* __restrict__ pos,
                              float* __restrict__ z){
  int idx = blockIdx.x * 256 + threadIdx.x; // 1024*128
  int bn = idx >> 7, d = idx & 127;
  int n = bn & 31;
  float a = pb[d] + pos[n*128 + d];
  for (int c = 0; c < 64; ++c) a = fmaf(pooled[bn*64 + c], pw[c*128 + d], a);
  z[idx] = a;
}

// ---------------- layernorm over 128, one wave per row; optional mask multiply ----------------
__global__ void ln128_kernel(const float* __restrict__ in, float* __restrict__ out,
                             const float* __restrict__ g, const float* __restrict__ b,
                             const float* __restrict__ mask){
  int row = blockIdx.x * 4 + (threadIdx.x >> 6);
  int lane = threadIdx.x & 63;
  const float* ir = in + (size_t)row * 128;
  float x0 = ir[lane], x1 = ir[lane + 64];
  float mean = waveReduceSum(x0 + x1) * (1.f/128.f);
  float d0 = x0 - mean, d1 = x1 - mean;
  float var = waveReduceSum(d0*d0 + d1*d1) * (1.f/128.f);
  float rstd = rsqrtf(var + 1e-5f);
  float o0 = d0*rstd*g[lane] + b[lane];
  float o1 = d1*rstd*g[lane+64] + b[lane+64];
  if (mask){ float mk = mask[row]; o0 *= mk; o1 *= mk; }
  out[row*128 + lane] = o0;
  out[row*128 + lane + 64] = o1;
}

// ---------------- generic small matmul: out[r,j] (= / +=) act(A[r,:]@W[:,j] + bias[j]) ----------------
__global__ void mm_kernel(const float* __restrict__ A, const float* __restrict__ Wm,
                          const float* __restrict__ bias, float* __restrict__ out,
                          int K, int N, int relu, int resadd){
  int idx = blockIdx.x * 256 + threadIdx.x;
  int r = idx / N, j = idx % N;
  float a = bias[j];
  const float* Ar = A + (size_t)r * K;
  for (int k = 0; k < K; ++k) a = fmaf(Ar[k], Wm[(size_t)k*N + j], a);
  if (relu) a = fmaxf(a, 0.f);
  if (resadd) a += out[idx];
  out[idx] = a;
}

// ---------------- attention for one (b,h): N=32 keys/queries, hd=16 ----------------
__global__ void attn_kernel(const float* __restrict__ qkv, const float* __restrict__ mask,
                            float* __restrict__ attn_o){
  int b = blockIdx.x >> 3, hh = blockIdx.x & 7;
  int tid = threadIdx.x;
  __shared__ float q[32][16], kk[32][16], vv[32][16], s[32][32];
  #pragma unroll
  for (int r = 0; r < 2; ++r){
    int lin = r*256 + tid;
    int n = lin >> 4, d = lin & 15;
    size_t base = (size_t)(b*32 + n)*384 + hh*16 + d;
    q[n][d]  = qkv[base];
    kk[n][d] = qkv[base + 128];
    vv[n][d] = qkv[base + 256];
  }
  __syncthreads();
  #pragma unroll
  for (int r = 0; r < 4; ++r){
    int lin = r*256 + tid;
    int qi = lin >> 5, ki = lin & 31;
    float a = 0.f;
    #pragma unroll
    for (int d = 0; d < 16; ++d) a = fmaf(q[qi][d], kk[ki][d], a);
    a *= 0.25f;
    if (mask[b*32 + ki] == 0.f) a = -1e9f;
    s[qi][ki] = a;
  }
  __syncthreads();
  if (tid < 32){
    float m = -1e30f;
    for (int ki = 0; ki < 32; ++ki) m = fmaxf(m, s[tid][ki]);
    float sum = 0.f;
    for (int ki = 0; ki < 32; ++ki){ float e = expf(s[tid][ki] - m); s[tid][ki] = e; sum += e; }
    float inv = 1.f / sum;
    for (int ki = 0; ki < 32; ++ki) s[tid][ki] *= inv;
  }
  __syncthreads();
  #pragma unroll
  for (int r = 0; r < 2; ++r){
    int lin = r*256 + tid;
    int qi = lin >> 4, d = lin & 15;
    float o = 0.f;
    #pragma unroll
    for (int ki = 0; ki < 32; ++ki) o = fmaf(s[qi][ki], vv[ki][d], o);
    attn_o[(size_t)(b*32 + qi)*128 + hh*16 + d] = o;
  }
}

// ---------------- per-batch router stats ----------------
__global__ void router_kernel(const float* __restrict__ ctx, const float* __restrict__ mask,
                              float* __restrict__ mean_ctx, float* __restrict__ router_in){
  int b = blockIdx.x;
  int d = threadIdx.x; // 128
  float s = 0.f, s2 = 0.f;
  for (int n = 0; n < 32; ++n){ float v = ctx[(size_t)(b*32+n)*128 + d]; s += v; s2 += v*v; }
  float cnt = 0.f;
  for (int n = 0; n < 32; ++n) cnt += mask[b*32 + n];
  cnt = fmaxf(cnt, 1.f);
  float mean = s / cnt;
  float var = s2 / cnt - mean*mean;
  mean_ctx[b*128 + d] = mean;
  router_in[b*256 + d] = mean;
  router_in[b*256 + 128 + d] = sqrtf(fmaxf(var, 1e-6f));
}

// ---------------- gate: logits, top2, softmax weights ----------------
__global__ void gate_kernel(const float* __restrict__ gin, const float* __restrict__ gw,
                            const float* __restrict__ gb, int ntok, int K,
                            int* __restrict__ ti, float* __restrict__ tw,
                            float* __restrict__ logits_out){
  int tok = blockIdx.x * 64 + threadIdx.x;
  if (tok >= ntok) return;
  float acc[16];
  #pragma unroll
  for (int e = 0; e < 16; ++e) acc[e] = gb[e];
  const float* gr = gin + (size_t)tok * K;
  for (int k = 0; k < K; ++k){
    float gv = gr[k];
    #pragma unroll
    for (int e = 0; e < 16; ++e) acc[e] = fmaf(gv, gw[k*16 + e], acc[e]);
  }
  if (logits_out){
    #pragma unroll
    for (int e = 0; e < 16; ++e) logits_out[tok*16 + e] = acc[e];
  }
  int i0 = 0; float v0 = acc[0];
  #pragma unroll
  for (int e = 1; e < 16; ++e) if (acc[e] > v0){ v0 = acc[e]; i0 = e; }
  int i1 = -1; float v1 = -1e30f;
  #pragma unroll
  for (int e = 0; e < 16; ++e) if (e != i0 && acc[e] > v1){ v1 = acc[e]; i1 = e; }
  float e1 = expf(v1 - v0);
  float den = 1.f / (1.f + e1);
  ti[tok*2] = i0; ti[tok*2+1] = i1;
  tw[tok*2] = den; tw[tok*2+1] = e1 * den;
}

// ---------------- MoE expert eval (top-2, weighted sum); optional mask multiply ----------------
__global__ void moe_expert_kernel(const float* __restrict__ xin, const int* __restrict__ ti,
                                  const float* __restrict__ tw,
                                  const float* __restrict__ w1, const float* __restrict__ b1,
                                  const float* __restrict__ w2, const float* __restrict__ b2,
                                  const float* __restrict__ mask, float* __restrict__ yout){
  int tok = blockIdx.x;
  int tid = threadIdx.x; // 256
  __shared__ float xs[128];
  __shared__ float h1[256];
  if (tid < 128) xs[tid] = xin[(size_t)tok*128 + tid];
  __syncthreads();
  float accv = 0.f;
  for (int kkk = 0; kkk < 2; ++kkk){
    int e = ti[tok*2 + kkk];
    float wv = tw[tok*2 + kkk];
    float a = b1[e*256 + tid];
    for (int k = 0; k < 128; ++k) a = fmaf(xs[k], w1[(size_t)(e*128 + k)*256 + tid], a);
    __syncthreads();           // prior h1 readers done
    h1[tid] = fmaxf(a, 0.f);
    __syncthreads();
    if (tid < 128){
      float o = b2[e*128 + tid];
      for (int k = 0; k < 256; ++k) o = fmaf(h1[k], w2[(size_t)(e*256 + k)*128 + tid], o);
      accv += wv * o;
    }
  }
  if (tid < 128){
    if (mask) accv *= mask[tok];
    yout[(size_t)tok*128 + tid] = accv;
  }
}

// ---------------- aux loss (single thread; 32 tokens x 16 experts) ----------------
__global__ void aux_kernel(const float* __restrict__ logits, const int* __restrict__ ti,
                           float* __restrict__ out_scalar){
  if (threadIdx.x != 0 || blockIdx.x != 0) return;
  float pm[16];
  for (int e = 0; e < 16; ++e) pm[e] = 0.f;
  for (int i = 0; i < 32; ++i){
    const float* row = logits + i*16;
    float m = -1e30f;
    for (int e = 0; e < 16; ++e) m = fmaxf(m, row[e]);
    float s = 0.f;
    float ex[16];
    for (int e = 0; e < 16; ++e){ ex[e] = expf(row[e] - m); s += ex[e]; }
    for (int e = 0; e < 16; ++e) pm[e] += ex[e] / s;
  }
  float cnt[16];
  for (int e = 0; e < 16; ++e) cnt[e] = 0.f;
  for (int i = 0; i < 64; ++i) cnt[ti[i]] += 1.f;
  float loss = 0.f;
  for (int e = 0; e < 16; ++e) loss += (pm[e] / 32.f) * (cnt[e] / 64.f);
  out_scalar[0] = 16.f * loss;
}

// ---------------- pred + rca heads ----------------
__global__ void heads_kernel(const float* __restrict__ st_last, const float* __restrict__ ctx,
                             const float* __restrict__ moe_f, const float* __restrict__ moe_rca,
                             const float* __restrict__ pred_w, const float* __restrict__ pred_b,
                             const float* __restrict__ rca_w, const float* __restrict__ rca_b,
                             float* __restrict__ out){
  int bn = blockIdx.x * 256 + threadIdx.x;
  if (bn >= 1024) return;
  int b = bn >> 5;
  float p0 = pred_b[0], p1 = pred_b[1], p2 = pred_b[2];
  float r = rca_b[0];
  for (int i = 0; i < 64; ++i){
    float v = st_last[(size_t)bn*64 + i];
    p0 = fmaf(v, pred_w[i*3+0], p0); p1 = fmaf(v, pred_w[i*3+1], p1); p2 = fmaf(v, pred_w[i*3+2], p2);
    r = fmaf(v, rca_w[i], r);
  }
  for (int i = 0; i < 128; ++i){
    float v = ctx[(size_t)bn*128 + i];
    int ii = 64 + i;
    p0 = fmaf(v, pred_w[ii*3+0], p0); p1 = fmaf(v, pred_w[ii*3+1], p1); p2 = fmaf(v, pred_w[ii*3+2], p2);
    r = fmaf(v, rca_w[ii], r);
  }
  for (int i = 0; i < 128; ++i){
    int ii = 192 + i;
    float vp = moe_f[(size_t)b*128 + i];
    p0 = fmaf(vp, pred_w[ii*3+0], p0); p1 = fmaf(vp, pred_w[ii*3+1], p1); p2 = fmaf(vp, pred_w[ii*3+2], p2);
    float vr = moe_rca[(size_t)bn*128 + i];
    r = fmaf(vr, rca_w[ii], r);
  }
  out[bn*3+0] = p0; out[bn*3+1] = p1; out[bn*3+2] = p2;
  out[3168 + bn] = r;
}

__global__ void fail_kernel(const float* __restrict__ moe_fail, const float* __restrict__ fw,
                            const float* __restrict__ fb, float* __restrict__ out){
  int idx = blockIdx.x * 128 + threadIdx.x;
  if (idx >= 96) return;
  int b = idx / 3, j = idx % 3;
  float a = fb[j];
  for (int k = 0; k < 128; ++k) a = fmaf(moe_fail[(size_t)b*128 + k], fw[k*3 + j], a);
  out[3072 + idx] = a;
}

// ================= host =================
extern "C" void kernel_launch(void* const* d_in, const int* in_sizes, int n_in,
                              void* d_out, int out_size, void* d_ws, size_t ws_size,
                              hipStream_t stream){
  const float* x        = (const float*)d_in[0];
  const float* mask     = (const float*)d_in[1];
  const float* proj_w   = (const float*)d_in[2];
  const float* proj_b   = (const float*)d_in[3];
  const float* tcn_w1   = (const float*)d_in[4];
  const float* tcn_b1   = (const float*)d_in[5];
  const float* tcn_w2   = (const float*)d_in[6];
  const float* tcn_b2   = (const float*)d_in[7];
  const float* tcn_ln_g = (const float*)d_in[8];
  const float* tcn_ln_b = (const float*)d_in[9];
  const float* pool_w   = (const float*)d_in[10];
  const float* pool_b   = (const float*)d_in[11];
  const float* pos_inter= (const float*)d_in[12];
  const float* tx_ln1_g = (const float*)d_in[13];
  const float* tx_ln1_b = (const float*)d_in[14];
  const float* tx_qkv_w = (const float*)d_in[15];
  const float* tx_qkv_b = (const float*)d_in[16];
  const float* tx_out_w = (const float*)d_in[17];
  const float* tx_out_b = (const float*)d_in[18];
  const float* tx_ln2_g = (const float*)d_in[19];
  const float* tx_ln2_b = (const float*)d_in[20];
  const float* tx_ff1_w = (const float*)d_in[21];
  const float* tx_ff1_b = (const float*)d_in[22];
  const float* tx_ff2_w = (const float*)d_in[23];
  const float* tx_ff2_b = (const float*)d_in[24];
  const float* tx_fln_g = (const float*)d_in[25];
  const float* tx_fln_b = (const float*)d_in[26];
  const float* exp_w1   = (const float*)d_in[27];
  const float* exp_b1   = (const float*)d_in[28];
  const float* exp_w2   = (const float*)d_in[29];
  const float* exp_b2   = (const float*)d_in[30];
  const float* gate_f_w = (const float*)d_in[31];
  const float* gate_f_b = (const float*)d_in[32];
  const float* gate_fail_w = (const float*)d_in[33];
  const float* gate_fail_b = (const float*)d_in[34];
  const float* gate_rca_w  = (const float*)d_in[35];
  const float* gate_rca_b  = (const float*)d_in[36];
  const float* pred_w   = (const float*)d_in[37];
  const float* pred_b   = (const float*)d_in[38];
  const float* fail_w   = (const float*)d_in[39];
  const float* fail_b   = (const float*)d_in[40];
  const float* rca_w    = (const float*)d_in[41];
  const float* rca_b    = (const float*)d_in[42];
  float* out = (float*)d_out;
  float* W = (float*)d_ws;

  // ---- workspace layout (float offsets) ----
  const size_t o_wt1 = 0, o_wt2 = 49152;
  const size_t o_pooled = 98304, o_stlast = 163840;
  const size_t o_z = 229376, o_y = 360448, o_qkv = 491520, o_attn = 884736;
  const size_t o_ff1 = 1015808, o_ctx = 1277952;
  const size_t o_meanctx = 1409024, o_router = 1413120;
  const size_t o_moef = 1421312, o_moefail = 1425408, o_moerca = 1429504;
  const size_t o_logitsf = 1560576, o_twf = 1561088, o_twfail = 1561152, o_twrca = 1561216;
  const size_t o_tif = 1563264, o_tifail = 1563328, o_tirca = 1563392;
  const size_t small_floats = 1572864; // 6 MiB of floats reserved

  // pick TCN chunk size from ws_size
  int cands[6] = {1024, 512, 256, 128, 64, 32};
  int CHUNK = 32;
  for (int i = 0; i < 6; ++i){
    size_t need = (small_floats + 2ull*(size_t)cands[i]*32768ull) * 4ull;
    if (need <= ws_size){ CHUNK = cands[i]; break; }
  }
  int nchunks = 1024 / CHUNK;
  float* hbuf = W + small_floats;
  float* obuf = hbuf + (size_t)CHUNK * 32768;

  // 1. transpose TCN weights
  transpose_w_kernel<<<192, 256, 0, stream>>>(tcn_w1, tcn_w2, W + o_wt1, W + o_wt2);

  // 2. per-chunk: proj+pe -> 4x(conv,conv+res) -> ln+pool
  for (int ch = 0; ch < nchunks; ++ch){
    int base = ch * CHUNK;
    proj_pe_kernel<<<CHUNK*128, 256, 0, stream>>>(x, proj_w, proj_b, hbuf, base);
    for (int l = 0; l < 4; ++l){
      int dil = 1 << l;
      tcn_conv_kernel<<<dim3(2, CHUNK), 256, 0, stream>>>(
          hbuf, obuf, nullptr, W + o_wt1 + l*12288, tcn_b1 + l*64, dil);
      tcn_conv_kernel<<<dim3(2, CHUNK), 256, 0, stream>>>(
          obuf, hbuf, hbuf, W + o_wt2 + l*12288, tcn_b2 + l*64, dil);
    }
    ln_pool_kernel<<<CHUNK, 256, 0, stream>>>(hbuf, tcn_ln_g, tcn_ln_b, mask,
                                              W + o_pooled, W + o_stlast, base);
  }

  // 3. z init
  z_init_kernel<<<512, 256, 0, stream>>>(W + o_pooled, pool_w, pool_b, pos_inter, W + o_z);

  // 4. transformer x2
  for (int l = 0; l < 2; ++l){
    ln128_kernel<<<256, 256, 0, stream>>>(W + o_z, W + o_y, tx_ln1_g + l*128, tx_ln1_b + l*128, nullptr);
    mm_kernel<<<1536, 256, 0, stream>>>(W + o_y, tx_qkv_w + (size_t)l*49152, tx_qkv_b + l*384,
                                        W + o_qkv, 128, 384, 0, 0);
    attn_kernel<<<256, 256, 0, stream>>>(W + o_qkv, mask, W + o_attn);
    mm_kernel<<<512, 256, 0, stream>>>(W + o_attn, tx_out_w + (size_t)l*16384, tx_out_b + l*128,
                                       W + o_z, 128, 128, 0, 1);
    ln128_kernel<<<256, 256, 0, stream>>>(W + o_z, W + o_y, tx_ln2_g + l*128, tx_ln2_b + l*128, nullptr);
    mm_kernel<<<1024, 256, 0, stream>>>(W + o_y, tx_ff1_w + (size_t)l*32768, tx_ff1_b + l*256,
                                        W + o_ff1, 128, 256, 1, 0);
    mm_kernel<<<512, 256, 0, stream>>>(W + o_ff1, tx_ff2_w + (size_t)l*32768, tx_ff2_b + l*128,
                                       W + o_z, 256, 128, 0, 1);
  }

  // 5. final LN -> ctx (masked)
  ln128_kernel<<<256, 256, 0, stream>>>(W + o_z, W + o_ctx, tx_fln_g, tx_fln_b, mask);

  // 6. router stats
  router_kernel<<<32, 128, 0, stream>>>(W + o_ctx, mask, W + o_meanctx, W + o_router);

  // 7. gates
  gate_kernel<<<1, 64, 0, stream>>>(W + o_router, gate_f_w, gate_f_b, 32, 256,
                                    (int*)(W + o_tif), W + o_twf, W + o_logitsf);
  gate_kernel<<<1, 64, 0, stream>>>(W + o_router, gate_fail_w, gate_fail_b, 32, 256,
                                    (int*)(W + o_tifail), W + o_twfail, nullptr);
  gate_kernel<<<16, 64, 0, stream>>>(W + o_ctx, gate_rca_w, gate_rca_b, 1024, 128,
                                     (int*)(W + o_tirca), W + o_twrca, nullptr);

  // 8. experts
  moe_expert_kernel<<<32, 256, 0, stream>>>(W + o_meanctx, (int*)(W + o_tif), W + o_twf,
                                            exp_w1, exp_b1, exp_w2, exp_b2, nullptr, W + o_moef);
  moe_expert_kernel<<<32, 256, 0, stream>>>(W + o_meanctx, (int*)(W + o_tifail), W + o_twfail,
                                            exp_w1, exp_b1, exp_w2, exp_b2, nullptr, W + o_moefail);
  moe_expert_kernel<<<1024, 256, 0, stream>>>(W + o_ctx, (int*)(W + o_tirca), W + o_twrca,
                                              exp_w1, exp_b1, exp_w2, exp_b2, mask, W + o_moerca);

  // 9. aux loss
  aux_kernel<<<1, 64, 0, stream>>>(W + o_logitsf, (int*)(W + o_tif), out + 4192);

  // 10. heads
  heads_kernel<<<4, 256, 0, stream>>>(W + o_stlast, W + o_ctx, W + o_moef, W + o_moerca,
                                      pred_w, pred_b, rca_w, rca_b, out);
  fail_kernel<<<1, 128, 0, stream>>>(W + o_moefail, fail_w, fail_b, out);
}

// Round 3
// 2379.565 us; speedup vs baseline: 1.0029x; 1.0029x over previous
//
#include <hip/hip_runtime.h>
#include <hip/hip_bf16.h>
#include <math.h>

// ---------------- constants ----------------
#define Bb 32
#define Ss 512
#define Nn 32
#define DTt 64
#define Dd 128
#define Ee 16
#define HEe 256
#define MOo 128

__device__ inline float waveReduceSum(float v){
  #pragma unroll
  for (int off = 32; off > 0; off >>= 1) v += __shfl_xor(v, off, 64);
  return v;
}

// ---------------- transpose TCN weights: w[layer][co][ci][k] -> wt[layer][k][ci][co] ----------------
__global__ void transpose_w_kernel(const float* __restrict__ w1, const float* __restrict__ w2,
                                   float* __restrict__ wt1, float* __restrict__ wt2){
  int idx = blockIdx.x * 256 + threadIdx.x;
  if (idx >= 4*64*64*3) return;
  int k = idx % 3;
  int ci = (idx/3) & 63;
  int co = (idx/192) & 63;
  int layer = idx / 12288;
  int dst = layer*12288 + k*4096 + ci*64 + co;
  wt1[dst] = w1[idx];
  wt2[dst] = w2[idx];
}

// ---------------- proj + positional encoding; h layout (bn_local, c, t) ----------------
__global__ void proj_pe_kernel(const float* __restrict__ x, const float* __restrict__ pw,
                               const float* __restrict__ pb, float* __restrict__ h, int chunk_base){
  int idx = blockIdx.x * 256 + threadIdx.x;
  int t = idx & 511;
  int c = (idx >> 9) & 63;
  int bnl = idx >> 15;
  int bn = chunk_base + bnl;
  int b = bn >> 5, n = bn & 31;
  float xv = x[(size_t)b*(Ss*Nn) + (size_t)t*Nn + n];
  // div = exp(-(ln 10000)/64 * (c & ~1))
  float ang = (float)t * expf(-0.14391156831f * (float)(c & ~1));
  float pe = (c & 1) ? cosf(ang) : sinf(ang);
  h[idx] = fmaf(xv, pw[c], pb[c]) + pe;
}

// ---------------- TCN causal dilated conv: out[co,t] = act(sum_{k,ci} wt[k][ci][co]*in[ci,t-(2-k)*dil] + b) ----------------
// if res != null:  out = relu( relu(conv+b) + res )   (res may alias out; per-thread same-element RMW)
__global__ __launch_bounds__(256) void tcn_conv_kernel(
    const float* __restrict__ in, float* __restrict__ out, const float* __restrict__ res,
    const float* __restrict__ wt, const float* __restrict__ bias, int dil){
  int t = blockIdx.x * 256 + threadIdx.x;
  int bn = blockIdx.y;
  const float* inb = in + (size_t)bn * (64*512);
  float acc[64];
  #pragma unroll
  for (int co = 0; co < 64; ++co) acc[co] = 0.f;
  #pragma unroll
  for (int k = 0; k < 3; ++k){
    int st = t - (2-k)*dil;
    if (st < 0) continue;
    const float* wk = wt + k*4096;
    for (int ci = 0; ci < 64; ++ci){
      float v = inb[ci*512 + st];
      const float* wp = wk + ci*64;   // uniform address -> scalar loads
      #pragma unroll
      for (int co = 0; co < 64; ++co) acc[co] = fmaf(v, wp[co], acc[co]);
    }
  }
  float* outb = out + (size_t)bn * (64*512);
  const float* resb = res ? res + (size_t)bn * (64*512) : nullptr;
  #pragma unroll
  for (int co = 0; co < 64; ++co){
    float a = fmaxf(acc[co] + bias[co], 0.f);
    if (resb) a = fmaxf(a + resb[co*512 + t], 0.f);
    outb[co*512 + t] = a;
  }
}

// ---------------- post-TCN layernorm (over c) + masked mean-pool over t + last-t extract ----------------
__global__ __launch_bounds__(256) void ln_pool_kernel(
    const float* __restrict__ h, const float* __restrict__ g, const float* __restrict__ bta,
    const float* __restrict__ mask, float* __restrict__ pooled, float* __restrict__ st_last,
    int chunk_base){
  __shared__ float tile[64][65];
  int bnl = blockIdx.x;
  int bn = chunk_base + bnl;
  int tid = threadIdx.x;
  const float* hb = h + (size_t)bnl * (64*512);
  float pool_acc = 0.f, last_val = 0.f;
  for (int ti2 = 0; ti2 < 8; ++ti2){
    int t0 = ti2 * 64;
    #pragma unroll
    for (int r = 0; r < 16; ++r){
      int lin = r*256 + tid;
      int c = lin >> 6, tt = lin & 63;
      tile[c][tt] = hb[c*512 + t0 + tt];
    }
    __syncthreads();
    if (tid < 64){
      float m = 0.f;
      for (int c = 0; c < 64; ++c) m += tile[c][tid];
      m *= (1.f/64.f);
      float var = 0.f;
      for (int c = 0; c < 64; ++c){ float d = tile[c][tid] - m; var += d*d; }
      var *= (1.f/64.f);
      float rstd = rsqrtf(var + 1e-5f);
      for (int c = 0; c < 64; ++c) tile[c][tid] = (tile[c][tid]-m)*rstd*g[c] + bta[c];
    }
    __syncthreads();
    if (tid < 64){
      float s = 0.f;
      for (int tt = 0; tt < 64; ++tt) s += tile[tid][tt];
      pool_acc += s;
      if (ti2 == 7) last_val = tile[tid][63];
    }
    __syncthreads();
  }
  if (tid < 64){
    float mk = mask[bn];
    pooled[(size_t)bn*64 + tid]  = pool_acc * (1.f/512.f) * mk;
    st_last[(size_t)bn*64 + tid] = last_val * mk;
  }
}

// ---------------- z init: z = pooled @ pool_w + pool_b + pos_inter[n] ----------------
__global__ void z_init_kernel(const float* __restrict__ pooled, const float* __restrict__ pw,
                              const float* __restrict__ pb, const float* __restrict__ pos,
                              float* __restrict__ z){
  int idx = blockIdx.x * 256 + threadIdx.x; // 1024*128
  int bn = idx >> 7, d = idx & 127;
  int n = bn & 31;
  float a = pb[d] + pos[n*128 + d];
  for (int c = 0; c < 64; ++c) a = fmaf(pooled[bn*64 + c], pw[c*128 + d], a);
  z[idx] = a;
}

// ---------------- layernorm over 128, one wave per row; optional mask multiply ----------------
__global__ void ln128_kernel(const float* __restrict__ in, float* __restrict__ out,
                             const float* __restrict__ g, const float* __restrict__ b,
                             const float* __restrict__ mask){
  int row = blockIdx.x * 4 + (threadIdx.x >> 6);
  int lane = threadIdx.x & 63;
  const float* ir = in + (size_t)row * 128;
  float x0 = ir[lane], x1 = ir[lane + 64];
  float mean = waveReduceSum(x0 + x1) * (1.f/128.f);
  float d0 = x0 - mean, d1 = x1 - mean;
  float var = waveReduceSum(d0*d0 + d1*d1) * (1.f/128.f);
  float rstd = rsqrtf(var + 1e-5f);
  float o0 = d0*rstd*g[lane] + b[lane];
  float o1 = d1*rstd*g[lane+64] + b[lane+64];
  if (mask){ float mk = mask[row]; o0 *= mk; o1 *= mk; }
  out[row*128 + lane] = o0;
  out[row*128 + lane + 64] = o1;
}

// ---------------- generic small matmul: out[r,j] (= / +=) act(A[r,:]@W[:,j] + bias[j]) ----------------
__global__ void mm_kernel(const float* __restrict__ A, const float* __restrict__ Wm,
                          const float* __restrict__ bias, float* __restrict__ out,
                          int K, int N, int relu, int resadd){
  int idx = blockIdx.x * 256 + threadIdx.x;
  int r = idx / N, j = idx % N;
  float a = bias[j];
  const float* Ar = A + (size_t)r * K;
  for (int k = 0; k < K; ++k) a = fmaf(Ar[k], Wm[(size_t)k*N + j], a);
  if (relu) a = fmaxf(a, 0.f);
  if (resadd) a += out[idx];
  out[idx] = a;
}

// ---------------- attention for one (b,h): N=32 keys/queries, hd=16 ----------------
__global__ void attn_kernel(const float* __restrict__ qkv, const float* __restrict__ mask,
                            float* __restrict__ attn_o){
  int b = blockIdx.x >> 3, hh = blockIdx.x & 7;
  int tid = threadIdx.x;
  __shared__ float q[32][16], kk[32][16], vv[32][16], s[32][32];
  #pragma unroll
  for (int r = 0; r < 2; ++r){
    int lin = r*256 + tid;
    int n = lin >> 4, d = lin & 15;
    size_t base = (size_t)(b*32 + n)*384 + hh*16 + d;
    q[n][d]  = qkv[base];
    kk[n][d] = qkv[base + 128];
    vv[n][d] = qkv[base + 256];
  }
  __syncthreads();
  #pragma unroll
  for (int r = 0; r < 4; ++r){
    int lin = r*256 + tid;
    int qi = lin >> 5, ki = lin & 31;
    float a = 0.f;
    #pragma unroll
    for (int d = 0; d < 16; ++d) a = fmaf(q[qi][d], kk[ki][d], a);
    a *= 0.25f;
    if (mask[b*32 + ki] == 0.f) a = -1e9f;
    s[qi][ki] = a;
  }
  __syncthreads();
  if (tid < 32){
    float m = -1e30f;
    for (int ki = 0; ki < 32; ++ki) m = fmaxf(m, s[tid][ki]);
    float sum = 0.f;
    for (int ki = 0; ki < 32; ++ki){ float e = expf(s[tid][ki] - m); s[tid][ki] = e; sum += e; }
    float inv = 1.f / sum;
    for (int ki = 0; ki < 32; ++ki) s[tid][ki] *= inv;
  }
  __syncthreads();
  #pragma unroll
  for (int r = 0; r < 2; ++r){
    int lin = r*256 + tid;
    int qi = lin >> 4, d = lin & 15;
    float o = 0.f;
    #pragma unroll
    for (int ki = 0; ki < 32; ++ki) o = fmaf(s[qi][ki], vv[ki][d], o);
    attn_o[(size_t)(b*32 + qi)*128 + hh*16 + d] = o;
  }
}

// ---------------- per-batch router stats ----------------
__global__ void router_kernel(const float* __restrict__ ctx, const float* __restrict__ mask,
                              float* __restrict__ mean_ctx, float* __restrict__ router_in){
  int b = blockIdx.x;
  int d = threadIdx.x; // 128
  float s = 0.f, s2 = 0.f;
  for (int n = 0; n < 32; ++n){ float v = ctx[(size_t)(b*32+n)*128 + d]; s += v; s2 += v*v; }
  float cnt = 0.f;
  for (int n = 0; n < 32; ++n) cnt += mask[b*32 + n];
  cnt = fmaxf(cnt, 1.f);
  float mean = s / cnt;
  float var = s2 / cnt - mean*mean;
  mean_ctx[b*128 + d] = mean;
  router_in[b*256 + d] = mean;
  router_in[b*256 + 128 + d] = sqrtf(fmaxf(var, 1e-6f));
}

// ---------------- gate: logits, top2, softmax weights ----------------
__global__ void gate_kernel(const float* __restrict__ gin, const float* __restrict__ gw,
                            const float* __restrict__ gb, int ntok, int K,
                            int* __restrict__ ti, float* __restrict__ tw,
                            float* __restrict__ logits_out){
  int tok = blockIdx.x * 64 + threadIdx.x;
  if (tok >= ntok) return;
  float acc[16];
  #pragma unroll
  for (int e = 0; e < 16; ++e) acc[e] = gb[e];
  const float* gr = gin + (size_t)tok * K;
  for (int k = 0; k < K; ++k){
    float gv = gr[k];
    #pragma unroll
    for (int e = 0; e < 16; ++e) acc[e] = fmaf(gv, gw[k*16 + e], acc[e]);
  }
  if (logits_out){
    #pragma unroll
    for (int e = 0; e < 16; ++e) logits_out[tok*16 + e] = acc[e];
  }
  int i0 = 0; float v0 = acc[0];
  #pragma unroll
  for (int e = 1; e < 16; ++e) if (acc[e] > v0){ v0 = acc[e]; i0 = e; }
  int i1 = -1; float v1 = -1e30f;
  #pragma unroll
  for (int e = 0; e < 16; ++e) if (e != i0 && acc[e] > v1){ v1 = acc[e]; i1 = e; }
  float e1 = expf(v1 - v0);
  float den = 1.f / (1.f + e1);
  ti[tok*2] = i0; ti[tok*2+1] = i1;
  tw[tok*2] = den; tw[tok*2+1] = e1 * den;
}

// ---------------- MoE expert eval (top-2, weighted sum); optional mask multiply ----------------
__global__ void moe_expert_kernel(const float* __restrict__ xin, const int* __restrict__ ti,
                                  const float* __restrict__ tw,
                                  const float* __restrict__ w1, const float* __restrict__ b1,
                                  const float* __restrict__ w2, const float* __restrict__ b2,
                                  const float* __restrict__ mask, float* __restrict__ yout){
  int tok = blockIdx.x;
  int tid = threadIdx.x; // 256
  __shared__ float xs[128];
  __shared__ float h1[256];
  if (tid < 128) xs[tid] = xin[(size_t)tok*128 + tid];
  __syncthreads();
  float accv = 0.f;
  for (int kkk = 0; kkk < 2; ++kkk){
    int e = ti[tok*2 + kkk];
    float wv = tw[tok*2 + kkk];
    float a = b1[e*256 + tid];
    for (int k = 0; k < 128; ++k) a = fmaf(xs[k], w1[(size_t)(e*128 + k)*256 + tid], a);
    __syncthreads();           // prior h1 readers done
    h1[tid] = fmaxf(a, 0.f);
    __syncthreads();
    if (tid < 128){
      float o = b2[e*128 + tid];
      for (int k = 0; k < 256; ++k) o = fmaf(h1[k], w2[(size_t)(e*256 + k)*128 + tid], o);
      accv += wv * o;
    }
  }
  if (tid < 128){
    if (mask) accv *= mask[tok];
    yout[(size_t)tok*128 + tid] = accv;
  }
}

// ---------------- aux loss (single thread; 32 tokens x 16 experts) ----------------
__global__ void aux_kernel(const float* __restrict__ logits, const int* __restrict__ ti,
                           float* __restrict__ out_scalar){
  if (threadIdx.x != 0 || blockIdx.x != 0) return;
  float pm[16];
  for (int e = 0; e < 16; ++e) pm[e] = 0.f;
  for (int i = 0; i < 32; ++i){
    const float* row = logits + i*16;
    float m = -1e30f;
    for (int e = 0; e < 16; ++e) m = fmaxf(m, row[e]);
    float s = 0.f;
    float ex[16];
    for (int e = 0; e < 16; ++e){ ex[e] = expf(row[e] - m); s += ex[e]; }
    for (int e = 0; e < 16; ++e) pm[e] += ex[e] / s;
  }
  float cnt[16];
  for (int e = 0; e < 16; ++e) cnt[e] = 0.f;
  for (int i = 0; i < 64; ++i) cnt[ti[i]] += 1.f;
  float loss = 0.f;
  for (int e = 0; e < 16; ++e) loss += (pm[e] / 32.f) * (cnt[e] / 64.f);
  out_scalar[0] = 16.f * loss;
}

// ---------------- pred + rca heads ----------------
__global__ void heads_kernel(const float* __restrict__ st_last, const float* __restrict__ ctx,
                             const float* __restrict__ moe_f, const float* __restrict__ moe_rca,
                             const float* __restrict__ pred_w, const float* __restrict__ pred_b,
                             const float* __restrict__ rca_w, const float* __restrict__ rca_b,
                             float* __restrict__ out){
  int bn = blockIdx.x * 256 + threadIdx.x;
  if (bn >= 1024) return;
  int b = bn >> 5;
  float p0 = pred_b[0], p1 = pred_b[1], p2 = pred_b[2];
  float r = rca_b[0];
  for (int i = 0; i < 64; ++i){
    float v = st_last[(size_t)bn*64 + i];
    p0 = fmaf(v, pred_w[i*3+0], p0); p1 = fmaf(v, pred_w[i*3+1], p1); p2 = fmaf(v, pred_w[i*3+2], p2);
    r = fmaf(v, rca_w[i], r);
  }
  for (int i = 0; i < 128; ++i){
    float v = ctx[(size_t)bn*128 + i];
    int ii = 64 + i;
    p0 = fmaf(v, pred_w[ii*3+0], p0); p1 = fmaf(v, pred_w[ii*3+1], p1); p2 = fmaf(v, pred_w[ii*3+2], p2);
    r = fmaf(v, rca_w[ii], r);
  }
  for (int i = 0; i < 128; ++i){
    int ii = 192 + i;
    float vp = moe_f[(size_t)b*128 + i];
    p0 = fmaf(vp, pred_w[ii*3+0], p0); p1 = fmaf(vp, pred_w[ii*3+1], p1); p2 = fmaf(vp, pred_w[ii*3+2], p2);
    float vr = moe_rca[(size_t)bn*128 + i];
    r = fmaf(vr, rca_w[ii], r);
  }
  out[bn*3+0] = p0; out[bn*3+1] = p1; out[bn*3+2] = p2;
  out[3168 + bn] = r;
}

__global__ void fail_kernel(const float* __restrict__ moe_fail, const float* __restrict__ fw,
                            const float* __restrict__ fb, float* __restrict__ out){
  int idx = blockIdx.x * 128 + threadIdx.x;
  if (idx >= 96) return;
  int b = idx / 3, j = idx % 3;
  float a = fb[j];
  for (int k = 0; k < 128; ++k) a = fmaf(moe_fail[(size_t)b*128 + k], fw[k*3 + j], a);
  out[3072 + idx] = a;
}

// ================= host =================
extern "C" void kernel_launch(void* const* d_in, const int* in_sizes, int n_in,
                              void* d_out, int out_size, void* d_ws, size_t ws_size,
                              hipStream_t stream){
  const float* x        = (const float*)d_in[0];
  const float* mask     = (const float*)d_in[1];
  const float* proj_w   = (const float*)d_in[2];
  const float* proj_b   = (const float*)d_in[3];
  const float* tcn_w1   = (const float*)d_in[4];
  const float* tcn_b1   = (const float*)d_in[5];
  const float* tcn_w2   = (const float*)d_in[6];
  const float* tcn_b2   = (const float*)d_in[7];
  const float* tcn_ln_g = (const float*)d_in[8];
  const float* tcn_ln_b = (const float*)d_in[9];
  const float* pool_w   = (const float*)d_in[10];
  const float* pool_b   = (const float*)d_in[11];
  const float* pos_inter= (const float*)d_in[12];
  const float* tx_ln1_g = (const float*)d_in[13];
  const float* tx_ln1_b = (const float*)d_in[14];
  const float* tx_qkv_w = (const float*)d_in[15];
  const float* tx_qkv_b = (const float*)d_in[16];
  const float* tx_out_w = (const float*)d_in[17];
  const float* tx_out_b = (const float*)d_in[18];
  const float* tx_ln2_g = (const float*)d_in[19];
  const float* tx_ln2_b = (const float*)d_in[20];
  const float* tx_ff1_w = (const float*)d_in[21];
  const float* tx_ff1_b = (const float*)d_in[22];
  const float* tx_ff2_w = (const float*)d_in[23];
  const float* tx_ff2_b = (const float*)d_in[24];
  const float* tx_fln_g = (const float*)d_in[25];
  const float* tx_fln_b = (const float*)d_in[26];
  const float* exp_w1   = (const float*)d_in[27];
  const float* exp_b1   = (const float*)d_in[28];
  const float* exp_w2   = (const float*)d_in[29];
  const float* exp_b2   = (const float*)d_in[30];
  const float* gate_f_w = (const float*)d_in[31];
  const float* gate_f_b = (const float*)d_in[32];
  const float* gate_fail_w = (const float*)d_in[33];
  const float* gate_fail_b = (const float*)d_in[34];
  const float* gate_rca_w  = (const float*)d_in[35];
  const float* gate_rca_b  = (const float*)d_in[36];
  const float* pred_w   = (const float*)d_in[37];
  const float* pred_b   = (const float*)d_in[38];
  const float* fail_w   = (const float*)d_in[39];
  const float* fail_b   = (const float*)d_in[40];
  const float* rca_w    = (const float*)d_in[41];
  const float* rca_b    = (const float*)d_in[42];
  float* out = (float*)d_out;
  float* W = (float*)d_ws;

  // ---- workspace layout (float offsets) ----
  const size_t o_wt1 = 0, o_wt2 = 49152;
  const size_t o_pooled = 98304, o_stlast = 163840;
  const size_t o_z = 229376, o_y = 360448, o_qkv = 491520, o_attn = 884736;
  const size_t o_ff1 = 1015808, o_ctx = 1277952;
  const size_t o_meanctx = 1409024, o_router = 1413120;
  const size_t o_moef = 1421312, o_moefail = 1425408, o_moerca = 1429504;
  const size_t o_logitsf = 1560576, o_twf = 1561088, o_twfail = 1561152, o_twrca = 1561216;
  const size_t o_tif = 1563264, o_tifail = 1563328, o_tirca = 1563392;
  const size_t small_floats = 1572864; // 6 MiB of floats reserved

  // pick TCN chunk size from ws_size
  int cands[6] = {1024, 512, 256, 128, 64, 32};
  int CHUNK = 32;
  for (int i = 0; i < 6; ++i){
    size_t need = (small_floats + 2ull*(size_t)cands[i]*32768ull) * 4ull;
    if (need <= ws_size){ CHUNK = cands[i]; break; }
  }
  int nchunks = 1024 / CHUNK;
  float* hbuf = W + small_floats;
  float* obuf = hbuf + (size_t)CHUNK * 32768;

  // 1. transpose TCN weights
  transpose_w_kernel<<<192, 256, 0, stream>>>(tcn_w1, tcn_w2, W + o_wt1, W + o_wt2);

  // 2. per-chunk: proj+pe -> 4x(conv,conv+res) -> ln+pool
  for (int ch = 0; ch < nchunks; ++ch){
    int base = ch * CHUNK;
    proj_pe_kernel<<<CHUNK*128, 256, 0, stream>>>(x, proj_w, proj_b, hbuf, base);
    for (int l = 0; l < 4; ++l){
      int dil = 1 << l;
      tcn_conv_kernel<<<dim3(2, CHUNK), 256, 0, stream>>>(
          hbuf, obuf, nullptr, W + o_wt1 + l*12288, tcn_b1 + l*64, dil);
      tcn_conv_kernel<<<dim3(2, CHUNK), 256, 0, stream>>>(
          obuf, hbuf, hbuf, W + o_wt2 + l*12288, tcn_b2 + l*64, dil);
    }
    ln_pool_kernel<<<CHUNK, 256, 0, stream>>>(hbuf, tcn_ln_g, tcn_ln_b, mask,
                                              W + o_pooled, W + o_stlast, base);
  }

  // 3. z init
  z_init_kernel<<<512, 256, 0, stream>>>(W + o_pooled, pool_w, pool_b, pos_inter, W + o_z);

  // 4. transformer x2
  for (int l = 0; l < 2; ++l){
    ln128_kernel<<<256, 256, 0, stream>>>(W + o_z, W + o_y, tx_ln1_g + l*128, tx_ln1_b + l*128, nullptr);
    mm_kernel<<<1536, 256, 0, stream>>>(W + o_y, tx_qkv_w + (size_t)l*49152, tx_qkv_b + l*384,
                                        W + o_qkv, 128, 384, 0, 0);
    attn_kernel<<<256, 256, 0, stream>>>(W + o_qkv, mask, W + o_attn);
    mm_kernel<<<512, 256, 0, stream>>>(W + o_attn, tx_out_w + (size_t)l*16384, tx_out_b + l*128,
                                       W + o_z, 128, 128, 0, 1);
    ln128_kernel<<<256, 256, 0, stream>>>(W + o_z, W + o_y, tx_ln2_g + l*128, tx_ln2_b + l*128, nullptr);
    mm_kernel<<<1024, 256, 0, stream>>>(W + o_y, tx_ff1_w + (size_t)l*32768, tx_ff1_b + l*256,
                                        W + o_ff1, 128, 256, 1, 0);
    mm_kernel<<<512, 256, 0, stream>>>(W + o_ff1, tx_ff2_w + (size_t)l*32768, tx_ff2_b + l*128,
                                       W + o_z, 256, 128, 0, 1);
  }

  // 5. final LN -> ctx (masked)
  ln128_kernel<<<256, 256, 0, stream>>>(W + o_z, W + o_ctx, tx_fln_g, tx_fln_b, mask);

  // 6. router stats
  router_kernel<<<32, 128, 0, stream>>>(W + o_ctx, mask, W + o_meanctx, W + o_router);

  // 7. gates
  gate_kernel<<<1, 64, 0, stream>>>(W + o_router, gate_f_w, gate_f_b, 32, 256,
                                    (int*)(W + o_tif), W + o_twf, W + o_logitsf);
  gate_kernel<<<1, 64, 0, stream>>>(W + o_router, gate_fail_w, gate_fail_b, 32, 256,
                                    (int*)(W + o_tifail), W + o_twfail, nullptr);
  gate_kernel<<<16, 64, 0, stream>>>(W + o_ctx, gate_rca_w, gate_rca_b, 1024, 128,
                                     (int*)(W + o_tirca), W + o_twrca, nullptr);

  // 8. experts
  moe_expert_kernel<<<32, 256, 0, stream>>>(W + o_meanctx, (int*)(W + o_tif), W + o_twf,
                                            exp_w1, exp_b1, exp_w2, exp_b2, nullptr, W + o_moef);
  moe_expert_kernel<<<32, 256, 0, stream>>>(W + o_meanctx, (int*)(W + o_tifail), W + o_twfail,
                                            exp_w1, exp_b1, exp_w2, exp_b2, nullptr, W + o_moefail);
  moe_expert_kernel<<<1024, 256, 0, stream>>>(W + o_ctx, (int*)(W + o_tirca), W + o_twrca,
                                              exp_w1, exp_b1, exp_w2, exp_b2, mask, W + o_moerca);

  // 9. aux loss
  aux_kernel<<<1, 64, 0, stream>>>(W + o_logitsf, (int*)(W + o_tif), out + 4192);

  // 10. heads
  heads_kernel<<<4, 256, 0, stream>>>(W + o_stlast, W + o_ctx, W + o_moef, W + o_moerca,
                                      pred_w, pred_b, rca_w, rca_b, out);
  fail_kernel<<<1, 128, 0, stream>>>(W + o_moefail, fail_w, fail_b, out);
}

// Round 4
// 1420.549 us; speedup vs baseline: 1.6800x; 1.6751x over previous
//
#include <hip/hip_runtime.h>
#include <hip/hip_bf16.h>
#include <math.h>

// ---------------- constants ----------------
#define Bb 32
#define Ss 512
#define Nn 32
#define DTt 64
#define Dd 128
#define Ee 16
#define HEe 256
#define MOo 128

typedef short short8v __attribute__((ext_vector_type(8)));
typedef float f32x4 __attribute__((ext_vector_type(4)));
typedef unsigned short ushort4v __attribute__((ext_vector_type(4)));

__device__ inline float waveReduceSum(float v){
  #pragma unroll
  for (int off = 32; off > 0; off >>= 1) v += __shfl_xor(v, off, 64);
  return v;
}

// bf16 helpers (manual RNE, bit-exact with __float2bfloat16 for finite values)
__device__ inline unsigned short f2bf(float x){
  unsigned int u = __builtin_bit_cast(unsigned int, x);
  unsigned int r = (u + 0x7FFFu + ((u >> 16) & 1u)) >> 16;
  return (unsigned short)r;
}
__device__ inline float bf2f(unsigned short u){
  unsigned int w = ((unsigned int)u) << 16;
  return __builtin_bit_cast(float, w);
}

// ============================================================================
// Weight transform: w[layer][co][ci][tap] -> MFMA A-fragment order, split hi/lo
// frag addr (ushort units): conv*24576 + (((tap*2+kk)*4+ct)*2+plane)*512 + lane*8 + j
// A[m=co%16][k=ci%32] : lane = (k/8)*16 + m, element j = k%8
// ============================================================================
__global__ void build_wfrag_kernel(const float* __restrict__ w1, const float* __restrict__ w2,
                                   unsigned short* __restrict__ wf){
  int idx = blockIdx.x * 256 + threadIdx.x;
  if (idx >= 98304) return;
  int conv = idx / 12288;
  int r = idx % 12288;
  int tap = r >> 12;            // 0..2
  int kk  = (r >> 11) & 1;
  int ct  = (r >> 9) & 3;
  int lane= (r >> 3) & 63;
  int j   = r & 7;
  int layer = conv >> 1;
  const float* src = (conv & 1) ? w2 : w1;
  int co = (ct << 4) + (lane & 15);
  int ci = (kk << 5) + ((lane >> 4) << 3) + j;
  float v = src[((layer * 64 + co) * 64 + ci) * 3 + tap];
  unsigned short hi = f2bf(v);
  unsigned short lo = f2bf(v - bf2f(hi));
  size_t base = (size_t)conv * 24576 + (size_t)(((tap * 2 + kk) * 4 + ct) * 2) * 512 + lane * 8 + j;
  wf[base] = hi;
  wf[base + 512] = lo;
}

// ============================================================================
// proj + positional encoding -> split-bf16 planes  h[bnl][t][plane(2)][c(64)]
// ============================================================================
__global__ __launch_bounds__(512) void proj_split_kernel(
    const float* __restrict__ x, const float* __restrict__ pw, const float* __restrict__ pb,
    unsigned short* __restrict__ hA, int halfbase){
  int bnl = blockIdx.x >> 2, cidx = blockIdx.x & 3;
  int tid = threadIdx.x;
  int t = (cidx << 7) + (tid >> 2);
  int c0 = (tid & 3) << 4;
  int bn = halfbase + bnl;
  int b = bn >> 5, n = bn & 31;
  float xv = x[((size_t)b << 14) + (t << 5) + n];
  unsigned short hi[16], lo[16];
  #pragma unroll
  for (int jj = 0; jj < 16; ++jj){
    int c = c0 + jj;
    float ang = (float)t * expf(-0.14391156831f * (float)(c & ~1));
    float pe = (c & 1) ? cosf(ang) : sinf(ang);
    float val = fmaf(xv, pw[c], pb[c]) + pe;
    unsigned short h = f2bf(val);
    hi[jj] = h;
    lo[jj] = f2bf(val - bf2f(h));
  }
  unsigned short* rowp = hA + (size_t)(bnl * 512 + t) * 128;
  short8v vh0, vh1, vl0, vl1;
  #pragma unroll
  for (int k = 0; k < 8; ++k){
    vh0[k] = (short)hi[k]; vh1[k] = (short)hi[k + 8];
    vl0[k] = (short)lo[k]; vl1[k] = (short)lo[k + 8];
  }
  *(short8v*)(rowp + c0)          = vh0;
  *(short8v*)(rowp + c0 + 8)      = vh1;
  *(short8v*)(rowp + 64 + c0)     = vl0;
  *(short8v*)(rowp + 64 + c0 + 8) = vl1;
}

// ============================================================================
// Fused TCN layer: h' = relu(relu(conv2(relu(conv1(h)+b1))+b2) + h)
// split-bf16 MFMA (hi*hi + hi*lo + lo*hi). Block = (bn, 128-t chunk), 512 thr.
// LDS: h tile 208 rows x 256B (swizzled) + o 192 rows x 256B (swizzled) = 100KiB
// ============================================================================
#define LDSO_OFF 53248

__global__ __launch_bounds__(512, 2) void tcn_pair_kernel(
    const unsigned short* __restrict__ hin, unsigned short* __restrict__ hout,
    const unsigned short* __restrict__ wfrag, const float* __restrict__ b1,
    const float* __restrict__ b2, int dil, int convbase){
  __shared__ __align__(16) char lds[102400];
  const int tid = threadIdx.x;
  const int lane = tid & 63, wid = tid >> 6;
  const int cp = wid & 1, tsub = wid >> 1;       // 2 co-pairs x 4 t-subtiles
  const int bnl = blockIdx.x >> 2, cidx = blockIdx.x & 3;
  const int t0 = cidx << 7;

  // ---- stage h rows t0-80 .. t0+127 (208 rows, zeros for t<0), swizzled ----
  for (int i = 0; i < 7; ++i){
    int idx = tid + i * 512;
    if (idx < 3328){
      int row = idx >> 4, c16 = idx & 15;
      int t = t0 - 80 + row;
      short8v v = {0,0,0,0,0,0,0,0};
      if (t >= 0) v = *(const short8v*)(hin + (size_t)(bnl * 512 + t) * 128 + c16 * 8);
      int addr = (row << 8) + (c16 << 4);
      addr ^= (row & 7) << 4;
      *(short8v*)(lds + addr) = v;
    }
  }

  // ---- A fragments for conv1 (hi/lo), this wave's 2 co-tiles ----
  short8v A1[3][2][2][2];
  #pragma unroll
  for (int tap = 0; tap < 3; ++tap)
    #pragma unroll
    for (int kk = 0; kk < 2; ++kk)
      #pragma unroll
      for (int cc = 0; cc < 2; ++cc)
        #pragma unroll
        for (int pl = 0; pl < 2; ++pl){
          int ct = 2 * cp + cc;
          A1[tap][kk][cc][pl] = *(const short8v*)(wfrag + (size_t)convbase * 24576 +
              (size_t)((((tap * 2 + kk) * 4 + ct) * 2 + pl)) * 512 + lane * 8);
        }
  __syncthreads();

  // ---- conv1: 3 supertiles covering o rows 0..191 (t = t0-64 .. t0+127) ----
  for (int S = 0; S < 3; ++S){
    f32x4 acc0 = {0.f,0.f,0.f,0.f}, acc1 = {0.f,0.f,0.f,0.f};
    int rowO = (S << 6) + (tsub << 4) + (lane & 15);   // per-lane o row
    #pragma unroll
    for (int tap = 0; tap < 3; ++tap){
      int shift = (2 - tap) * dil;
      int rowB = rowO + 16 - shift;                    // h-space row
      int sw = (rowB & 7) << 4;
      #pragma unroll
      for (int kk = 0; kk < 2; ++kk){
        int base = (rowB << 8) + (kk << 6) + ((lane >> 4) << 4);
        short8v Bhi = *(const short8v*)(lds + (base ^ sw));
        short8v Blo = *(const short8v*)(lds + ((base + 128) ^ sw));
        acc0 = __builtin_amdgcn_mfma_f32_16x16x32_bf16(A1[tap][kk][0][0], Bhi, acc0, 0, 0, 0);
        acc0 = __builtin_amdgcn_mfma_f32_16x16x32_bf16(A1[tap][kk][0][0], Blo, acc0, 0, 0, 0);
        acc0 = __builtin_amdgcn_mfma_f32_16x16x32_bf16(A1[tap][kk][0][1], Bhi, acc0, 0, 0, 0);
        acc1 = __builtin_amdgcn_mfma_f32_16x16x32_bf16(A1[tap][kk][1][0], Bhi, acc1, 0, 0, 0);
        acc1 = __builtin_amdgcn_mfma_f32_16x16x32_bf16(A1[tap][kk][1][0], Blo, acc1, 0, 0, 0);
        acc1 = __builtin_amdgcn_mfma_f32_16x16x32_bf16(A1[tap][kk][1][1], Bhi, acc1, 0, 0, 0);
      }
    }
    // epilogue: o = relu(acc + b1), zero for t<0, split, store to lds_o
    int t_out = t0 - 64 + rowO;
    int swO = (rowO & 7) << 4;
    #pragma unroll
    for (int cc = 0; cc < 2; ++cc){
      int ct = 2 * cp + cc;
      int cobase = (ct << 4) + ((lane >> 4) << 2);
      ushort4v hi4, lo4;
      #pragma unroll
      for (int r = 0; r < 4; ++r){
        float a = (cc == 0) ? acc0[r] : acc1[r];
        float v = fmaxf(a + b1[cobase + r], 0.f);
        if (t_out < 0) v = 0.f;
        unsigned short h = f2bf(v);
        hi4[r] = h;
        lo4[r] = f2bf(v - bf2f(h));
      }
      int ob = LDSO_OFF + (rowO << 8) + (cobase << 1);
      *(ushort4v*)(lds + (ob ^ swO)) = hi4;
      *(ushort4v*)(lds + ((ob + 128) ^ swO)) = lo4;
    }
  }

  // ---- A fragments for conv2 ----
  short8v A2[3][2][2][2];
  #pragma unroll
  for (int tap = 0; tap < 3; ++tap)
    #pragma unroll
    for (int kk = 0; kk < 2; ++kk)
      #pragma unroll
      for (int cc = 0; cc < 2; ++cc)
        #pragma unroll
        for (int pl = 0; pl < 2; ++pl){
          int ct = 2 * cp + cc;
          A2[tap][kk][cc][pl] = *(const short8v*)(wfrag + (size_t)(convbase + 1) * 24576 +
              (size_t)((((tap * 2 + kk) * 4 + ct) * 2 + pl)) * 512 + lane * 8);
        }
  __syncthreads();   // all o writes visible

  // ---- conv2: 2 supertiles covering t = t0 .. t0+127 ----
  for (int S = 0; S < 2; ++S){
    f32x4 acc0 = {0.f,0.f,0.f,0.f}, acc1 = {0.f,0.f,0.f,0.f};
    int tt = (S << 6) + (tsub << 4) + (lane & 15);     // t - t0
    #pragma unroll
    for (int tap = 0; tap < 3; ++tap){
      int shift = (2 - tap) * dil;
      int rowB = tt + 64 - shift;                      // o-space row
      int sw = (rowB & 7) << 4;
      #pragma unroll
      for (int kk = 0; kk < 2; ++kk){
        int base = LDSO_OFF + (rowB << 8) + (kk << 6) + ((lane >> 4) << 4);
        short8v Bhi = *(const short8v*)(lds + (base ^ sw));
        short8v Blo = *(const short8v*)(lds + ((base + 128) ^ sw));
        acc0 = __builtin_amdgcn_mfma_f32_16x16x32_bf16(A2[tap][kk][0][0], Bhi, acc0, 0, 0, 0);
        acc0 = __builtin_amdgcn_mfma_f32_16x16x32_bf16(A2[tap][kk][0][0], Blo, acc0, 0, 0, 0);
        acc0 = __builtin_amdgcn_mfma_f32_16x16x32_bf16(A2[tap][kk][0][1], Bhi, acc0, 0, 0, 0);
        acc1 = __builtin_amdgcn_mfma_f32_16x16x32_bf16(A2[tap][kk][1][0], Bhi, acc1, 0, 0, 0);
        acc1 = __builtin_amdgcn_mfma_f32_16x16x32_bf16(A2[tap][kk][1][0], Blo, acc1, 0, 0, 0);
        acc1 = __builtin_amdgcn_mfma_f32_16x16x32_bf16(A2[tap][kk][1][1], Bhi, acc1, 0, 0, 0);
      }
    }
    // epilogue: h' = relu(relu(acc + b2) + h_old); split; store to global
    int rowH = tt + 80;                                // h-space row (residual)
    int swH = (rowH & 7) << 4;
    int t = t0 + tt;
    #pragma unroll
    for (int cc = 0; cc < 2; ++cc){
      int ct = 2 * cp + cc;
      int cobase = (ct << 4) + ((lane >> 4) << 2);
      int rb = (rowH << 8) + (cobase << 1);
      ushort4v rhi = *(const ushort4v*)(lds + (rb ^ swH));
      ushort4v rlo = *(const ushort4v*)(lds + ((rb + 128) ^ swH));
      ushort4v hi4, lo4;
      #pragma unroll
      for (int r = 0; r < 4; ++r){
        float a = (cc == 0) ? acc0[r] : acc1[r];
        float v = fmaxf(a + b2[cobase + r], 0.f);
        v = fmaxf(v + bf2f(rhi[r]) + bf2f(rlo[r]), 0.f);
        unsigned short h = f2bf(v);
        hi4[r] = h;
        lo4[r] = f2bf(v - bf2f(h));
      }
      unsigned short* orow = hout + (size_t)(bnl * 512 + t) * 128;
      *(ushort4v*)(orow + cobase)      = hi4;
      *(ushort4v*)(orow + 64 + cobase) = lo4;
    }
  }
}

// ============================================================================
// post-TCN layernorm + masked mean-pool + last-t. One block per bn; wave = 64 rows.
// ============================================================================
__global__ __launch_bounds__(512) void ln_pool_split_kernel(
    const unsigned short* __restrict__ hin, const float* __restrict__ g,
    const float* __restrict__ bta, const float* __restrict__ mask,
    float* __restrict__ pooled, float* __restrict__ st_last, int halfbase){
  __shared__ float part[512];
  __shared__ float lastv[64];
  int tid = threadIdx.x;
  int s = tid >> 6, c = tid & 63;
  int bnl = blockIdx.x;
  int bn = halfbase + bnl;
  float gc = g[c], bc = bta[c];
  float acc = 0.f, last = 0.f;
  for (int r0 = 0; r0 < 64; ++r0){
    int r = (s << 6) + r0;
    const unsigned short* rp = hin + (size_t)(bnl * 512 + r) * 128;
    float val = bf2f(rp[c]) + bf2f(rp[64 + c]);
    float sum = val, sq = val * val;
    #pragma unroll
    for (int off = 32; off > 0; off >>= 1){
      sum += __shfl_xor(sum, off, 64);
      sq  += __shfl_xor(sq, off, 64);
    }
    float mean = sum * (1.f / 64.f);
    float var = sq * (1.f / 64.f) - mean * mean;
    float rstd = rsqrtf(var + 1e-5f);
    float o = (val - mean) * rstd * gc + bc;
    acc += o;
    if (r == 511) last = o;
  }
  part[tid] = acc;
  if (s == 7) lastv[c] = last;
  __syncthreads();
  if (tid < 64){
    float tot = 0.f;
    #pragma unroll
    for (int ss = 0; ss < 8; ++ss) tot += part[(ss << 6) + tid];
    float mk = mask[bn];
    pooled[(size_t)bn * 64 + tid]  = tot * (1.f / 512.f) * mk;
    st_last[(size_t)bn * 64 + tid] = lastv[tid] * mk;
  }
}

// ---------------- z init: z = pooled @ pool_w + pool_b + pos_inter[n] ----------------
__global__ void z_init_kernel(const float* __restrict__ pooled, const float* __restrict__ pw,
                              const float* __restrict__ pb, const float* __restrict__ pos,
                              float* __restrict__ z){
  int idx = blockIdx.x * 256 + threadIdx.x; // 1024*128
  int bn = idx >> 7, d = idx & 127;
  int n = bn & 31;
  float a = pb[d] + pos[n*128 + d];
  for (int c = 0; c < 64; ++c) a = fmaf(pooled[bn*64 + c], pw[c*128 + d], a);
  z[idx] = a;
}

// ---------------- layernorm over 128, one wave per row; optional mask multiply ----------------
__global__ void ln128_kernel(const float* __restrict__ in, float* __restrict__ out,
                             const float* __restrict__ g, const float* __restrict__ b,
                             const float* __restrict__ mask){
  int row = blockIdx.x * 4 + (threadIdx.x >> 6);
  int lane = threadIdx.x & 63;
  const float* ir = in + (size_t)row * 128;
  float x0 = ir[lane], x1 = ir[lane + 64];
  float mean = waveReduceSum(x0 + x1) * (1.f/128.f);
  float d0 = x0 - mean, d1 = x1 - mean;
  float var = waveReduceSum(d0*d0 + d1*d1) * (1.f/128.f);
  float rstd = rsqrtf(var + 1e-5f);
  float o0 = d0*rstd*g[lane] + b[lane];
  float o1 = d1*rstd*g[lane+64] + b[lane+64];
  if (mask){ float mk = mask[row]; o0 *= mk; o1 *= mk; }
  out[row*128 + lane] = o0;
  out[row*128 + lane + 64] = o1;
}

// ---------------- generic small matmul: out[r,j] (= / +=) act(A[r,:]@W[:,j] + bias[j]) ----------------
__global__ void mm_kernel(const float* __restrict__ A, const float* __restrict__ Wm,
                          const float* __restrict__ bias, float* __restrict__ out,
                          int K, int N, int relu, int resadd){
  int idx = blockIdx.x * 256 + threadIdx.x;
  int r = idx / N, j = idx % N;
  float a = bias[j];
  const float* Ar = A + (size_t)r * K;
  for (int k = 0; k < K; ++k) a = fmaf(Ar[k], Wm[(size_t)k*N + j], a);
  if (relu) a = fmaxf(a, 0.f);
  if (resadd) a += out[idx];
  out[idx] = a;
}

// ---------------- attention for one (b,h): N=32 keys/queries, hd=16 ----------------
__global__ void attn_kernel(const float* __restrict__ qkv, const float* __restrict__ mask,
                            float* __restrict__ attn_o){
  int b = blockIdx.x >> 3, hh = blockIdx.x & 7;
  int tid = threadIdx.x;
  __shared__ float q[32][16], kk[32][16], vv[32][16], s[32][32];
  #pragma unroll
  for (int r = 0; r < 2; ++r){
    int lin = r*256 + tid;
    int n = lin >> 4, d = lin & 15;
    size_t base = (size_t)(b*32 + n)*384 + hh*16 + d;
    q[n][d]  = qkv[base];
    kk[n][d] = qkv[base + 128];
    vv[n][d] = qkv[base + 256];
  }
  __syncthreads();
  #pragma unroll
  for (int r = 0; r < 4; ++r){
    int lin = r*256 + tid;
    int qi = lin >> 5, ki = lin & 31;
    float a = 0.f;
    #pragma unroll
    for (int d = 0; d < 16; ++d) a = fmaf(q[qi][d], kk[ki][d], a);
    a *= 0.25f;
    if (mask[b*32 + ki] == 0.f) a = -1e9f;
    s[qi][ki] = a;
  }
  __syncthreads();
  if (tid < 32){
    float m = -1e30f;
    for (int ki = 0; ki < 32; ++ki) m = fmaxf(m, s[tid][ki]);
    float sum = 0.f;
    for (int ki = 0; ki < 32; ++ki){ float e = expf(s[tid][ki] - m); s[tid][ki] = e; sum += e; }
    float inv = 1.f / sum;
    for (int ki = 0; ki < 32; ++ki) s[tid][ki] *= inv;
  }
  __syncthreads();
  #pragma unroll
  for (int r = 0; r < 2; ++r){
    int lin = r*256 + tid;
    int qi = lin >> 4, d = lin & 15;
    float o = 0.f;
    #pragma unroll
    for (int ki = 0; ki < 32; ++ki) o = fmaf(s[qi][ki], vv[ki][d], o);
    attn_o[(size_t)(b*32 + qi)*128 + hh*16 + d] = o;
  }
}

// ---------------- per-batch router stats ----------------
__global__ void router_kernel(const float* __restrict__ ctx, const float* __restrict__ mask,
                              float* __restrict__ mean_ctx, float* __restrict__ router_in){
  int b = blockIdx.x;
  int d = threadIdx.x; // 128
  float s = 0.f, s2 = 0.f;
  for (int n = 0; n < 32; ++n){ float v = ctx[(size_t)(b*32+n)*128 + d]; s += v; s2 += v*v; }
  float cnt = 0.f;
  for (int n = 0; n < 32; ++n) cnt += mask[b*32 + n];
  cnt = fmaxf(cnt, 1.f);
  float mean = s / cnt;
  float var = s2 / cnt - mean*mean;
  mean_ctx[b*128 + d] = mean;
  router_in[b*256 + d] = mean;
  router_in[b*256 + 128 + d] = sqrtf(fmaxf(var, 1e-6f));
}

// ---------------- gate: logits, top2, softmax weights ----------------
__global__ void gate_kernel(const float* __restrict__ gin, const float* __restrict__ gw,
                            const float* __restrict__ gb, int ntok, int K,
                            int* __restrict__ ti, float* __restrict__ tw,
                            float* __restrict__ logits_out){
  int tok = blockIdx.x * 64 + threadIdx.x;
  if (tok >= ntok) return;
  float acc[16];
  #pragma unroll
  for (int e = 0; e < 16; ++e) acc[e] = gb[e];
  const float* gr = gin + (size_t)tok * K;
  for (int k = 0; k < K; ++k){
    float gv = gr[k];
    #pragma unroll
    for (int e = 0; e < 16; ++e) acc[e] = fmaf(gv, gw[k*16 + e], acc[e]);
  }
  if (logits_out){
    #pragma unroll
    for (int e = 0; e < 16; ++e) logits_out[tok*16 + e] = acc[e];
  }
  int i0 = 0; float v0 = acc[0];
  #pragma unroll
  for (int e = 1; e < 16; ++e) if (acc[e] > v0){ v0 = acc[e]; i0 = e; }
  int i1 = -1; float v1 = -1e30f;
  #pragma unroll
  for (int e = 0; e < 16; ++e) if (e != i0 && acc[e] > v1){ v1 = acc[e]; i1 = e; }
  float e1 = expf(v1 - v0);
  float den = 1.f / (1.f + e1);
  ti[tok*2] = i0; ti[tok*2+1] = i1;
  tw[tok*2] = den; tw[tok*2+1] = e1 * den;
}

// ---------------- MoE expert eval (top-2, weighted sum); optional mask multiply ----------------
__global__ void moe_expert_kernel(const float* __restrict__ xin, const int* __restrict__ ti,
                                  const float* __restrict__ tw,
                                  const float* __restrict__ w1, const float* __restrict__ b1,
                                  const float* __restrict__ w2, const float* __restrict__ b2,
                                  const float* __restrict__ mask, float* __restrict__ yout){
  int tok = blockIdx.x;
  int tid = threadIdx.x; // 256
  __shared__ float xs[128];
  __shared__ float h1[256];
  if (tid < 128) xs[tid] = xin[(size_t)tok*128 + tid];
  __syncthreads();
  float accv = 0.f;
  for (int kkk = 0; kkk < 2; ++kkk){
    int e = ti[tok*2 + kkk];
    float wv = tw[tok*2 + kkk];
    float a = b1[e*256 + tid];
    for (int k = 0; k < 128; ++k) a = fmaf(xs[k], w1[(size_t)(e*128 + k)*256 + tid], a);
    __syncthreads();           // prior h1 readers done
    h1[tid] = fmaxf(a, 0.f);
    __syncthreads();
    if (tid < 128){
      float o = b2[e*128 + tid];
      for (int k = 0; k < 256; ++k) o = fmaf(h1[k], w2[(size_t)(e*256 + k)*128 + tid], o);
      accv += wv * o;
    }
  }
  if (tid < 128){
    if (mask) accv *= mask[tok];
    yout[(size_t)tok*128 + tid] = accv;
  }
}

// ---------------- aux loss (single thread; 32 tokens x 16 experts) ----------------
__global__ void aux_kernel(const float* __restrict__ logits, const int* __restrict__ ti,
                           float* __restrict__ out_scalar){
  if (threadIdx.x != 0 || blockIdx.x != 0) return;
  float pm[16];
  for (int e = 0; e < 16; ++e) pm[e] = 0.f;
  for (int i = 0; i < 32; ++i){
    const float* row = logits + i*16;
    float m = -1e30f;
    for (int e = 0; e < 16; ++e) m = fmaxf(m, row[e]);
    float s = 0.f;
    float ex[16];
    for (int e = 0; e < 16; ++e){ ex[e] = expf(row[e] - m); s += ex[e]; }
    for (int e = 0; e < 16; ++e) pm[e] += ex[e] / s;
  }
  float cnt[16];
  for (int e = 0; e < 16; ++e) cnt[e] = 0.f;
  for (int i = 0; i < 64; ++i) cnt[ti[i]] += 1.f;
  float loss = 0.f;
  for (int e = 0; e < 16; ++e) loss += (pm[e] / 32.f) * (cnt[e] / 64.f);
  out_scalar[0] = 16.f * loss;
}

// ---------------- pred + rca heads ----------------
__global__ void heads_kernel(const float* __restrict__ st_last, const float* __restrict__ ctx,
                             const float* __restrict__ moe_f, const float* __restrict__ moe_rca,
                             const float* __restrict__ pred_w, const float* __restrict__ pred_b,
                             const float* __restrict__ rca_w, const float* __restrict__ rca_b,
                             float* __restrict__ out){
  int bn = blockIdx.x * 256 + threadIdx.x;
  if (bn >= 1024) return;
  int b = bn >> 5;
  float p0 = pred_b[0], p1 = pred_b[1], p2 = pred_b[2];
  float r = rca_b[0];
  for (int i = 0; i < 64; ++i){
    float v = st_last[(size_t)bn*64 + i];
    p0 = fmaf(v, pred_w[i*3+0], p0); p1 = fmaf(v, pred_w[i*3+1], p1); p2 = fmaf(v, pred_w[i*3+2], p2);
    r = fmaf(v, rca_w[i], r);
  }
  for (int i = 0; i < 128; ++i){
    float v = ctx[(size_t)bn*128 + i];
    int ii = 64 + i;
    p0 = fmaf(v, pred_w[ii*3+0], p0); p1 = fmaf(v, pred_w[ii*3+1], p1); p2 = fmaf(v, pred_w[ii*3+2], p2);
    r = fmaf(v, rca_w[ii], r);
  }
  for (int i = 0; i < 128; ++i){
    int ii = 192 + i;
    float vp = moe_f[(size_t)b*128 + i];
    p0 = fmaf(vp, pred_w[ii*3+0], p0); p1 = fmaf(vp, pred_w[ii*3+1], p1); p2 = fmaf(vp, pred_w[ii*3+2], p2);
    float vr = moe_rca[(size_t)bn*128 + i];
    r = fmaf(vr, rca_w[ii], r);
  }
  out[bn*3+0] = p0; out[bn*3+1] = p1; out[bn*3+2] = p2;
  out[3168 + bn] = r;
}

__global__ void fail_kernel(const float* __restrict__ moe_fail, const float* __restrict__ fw,
                            const float* __restrict__ fb, float* __restrict__ out){
  int idx = blockIdx.x * 128 + threadIdx.x;
  if (idx >= 96) return;
  int b = idx / 3, j = idx % 3;
  float a = fb[j];
  for (int k = 0; k < 128; ++k) a = fmaf(moe_fail[(size_t)b*128 + k], fw[k*3 + j], a);
  out[3072 + idx] = a;
}

// ================= host =================
extern "C" void kernel_launch(void* const* d_in, const int* in_sizes, int n_in,
                              void* d_out, int out_size, void* d_ws, size_t ws_size,
                              hipStream_t stream){
  const float* x        = (const float*)d_in[0];
  const float* mask     = (const float*)d_in[1];
  const float* proj_w   = (const float*)d_in[2];
  const float* proj_b   = (const float*)d_in[3];
  const float* tcn_w1   = (const float*)d_in[4];
  const float* tcn_b1   = (const float*)d_in[5];
  const float* tcn_w2   = (const float*)d_in[6];
  const float* tcn_b2   = (const float*)d_in[7];
  const float* tcn_ln_g = (const float*)d_in[8];
  const float* tcn_ln_b = (const float*)d_in[9];
  const float* pool_w   = (const float*)d_in[10];
  const float* pool_b   = (const float*)d_in[11];
  const float* pos_inter= (const float*)d_in[12];
  const float* tx_ln1_g = (const float*)d_in[13];
  const float* tx_ln1_b = (const float*)d_in[14];
  const float* tx_qkv_w = (const float*)d_in[15];
  const float* tx_qkv_b = (const float*)d_in[16];
  const float* tx_out_w = (const float*)d_in[17];
  const float* tx_out_b = (const float*)d_in[18];
  const float* tx_ln2_g = (const float*)d_in[19];
  const float* tx_ln2_b = (const float*)d_in[20];
  const float* tx_ff1_w = (const float*)d_in[21];
  const float* tx_ff1_b = (const float*)d_in[22];
  const float* tx_ff2_w = (const float*)d_in[23];
  const float* tx_ff2_b = (const float*)d_in[24];
  const float* tx_fln_g = (const float*)d_in[25];
  const float* tx_fln_b = (const float*)d_in[26];
  const float* exp_w1   = (const float*)d_in[27];
  const float* exp_b1   = (const float*)d_in[28];
  const float* exp_w2   = (const float*)d_in[29];
  const float* exp_b2   = (const float*)d_in[30];
  const float* gate_f_w = (const float*)d_in[31];
  const float* gate_f_b = (const float*)d_in[32];
  const float* gate_fail_w = (const float*)d_in[33];
  const float* gate_fail_b = (const float*)d_in[34];
  const float* gate_rca_w  = (const float*)d_in[35];
  const float* gate_rca_b  = (const float*)d_in[36];
  const float* pred_w   = (const float*)d_in[37];
  const float* pred_b   = (const float*)d_in[38];
  const float* fail_w   = (const float*)d_in[39];
  const float* fail_b   = (const float*)d_in[40];
  const float* rca_w    = (const float*)d_in[41];
  const float* rca_b    = (const float*)d_in[42];
  float* out = (float*)d_out;
  float* W = (float*)d_ws;

  // ---- small-scratch layout (float offsets, unchanged tail) ----
  const size_t o_pooled = 98304, o_stlast = 163840;
  const size_t o_z = 229376, o_y = 360448, o_qkv = 491520, o_attn = 884736;
  const size_t o_ff1 = 1015808, o_ctx = 1277952;
  const size_t o_meanctx = 1409024, o_router = 1413120;
  const size_t o_moef = 1421312, o_moefail = 1425408, o_moerca = 1429504;
  const size_t o_logitsf = 1560576, o_twf = 1561088, o_twfail = 1561152, o_twrca = 1561216;
  const size_t o_tif = 1563264, o_tifail = 1563328, o_tirca = 1563392;

  // big buffers after the 6 MiB small region (total ws use ~135 MiB)
  unsigned short* wfragU = (unsigned short*)((char*)d_ws + 6291456);          // 786,432 B
  unsigned short* hA     = (unsigned short*)((char*)d_ws + 7077888);          // 67,108,864 B
  unsigned short* hB     = hA + 33554432;                                     // 67,108,864 B

  // 1. weight fragments (split hi/lo, MFMA layout)
  build_wfrag_kernel<<<384, 256, 0, stream>>>(tcn_w1, tcn_w2, wfragU);

  // 2. front-end in two bn-halves: proj -> 4 fused layers -> ln+pool
  for (int half = 0; half < 2; ++half){
    int hb = half * 512;
    proj_split_kernel<<<2048, 512, 0, stream>>>(x, proj_w, proj_b, hA, hb);
    tcn_pair_kernel<<<2048, 512, 0, stream>>>(hA, hB, wfragU, tcn_b1,       tcn_b2,       1, 0);
    tcn_pair_kernel<<<2048, 512, 0, stream>>>(hB, hA, wfragU, tcn_b1 + 64,  tcn_b2 + 64,  2, 2);
    tcn_pair_kernel<<<2048, 512, 0, stream>>>(hA, hB, wfragU, tcn_b1 + 128, tcn_b2 + 128, 4, 4);
    tcn_pair_kernel<<<2048, 512, 0, stream>>>(hB, hA, wfragU, tcn_b1 + 192, tcn_b2 + 192, 8, 6);
    ln_pool_split_kernel<<<512, 512, 0, stream>>>(hA, tcn_ln_g, tcn_ln_b, mask,
                                                  W + o_pooled, W + o_stlast, hb);
  }

  // 3. z init
  z_init_kernel<<<512, 256, 0, stream>>>(W + o_pooled, pool_w, pool_b, pos_inter, W + o_z);

  // 4. transformer x2
  for (int l = 0; l < 2; ++l){
    ln128_kernel<<<256, 256, 0, stream>>>(W + o_z, W + o_y, tx_ln1_g + l*128, tx_ln1_b + l*128, nullptr);
    mm_kernel<<<1536, 256, 0, stream>>>(W + o_y, tx_qkv_w + (size_t)l*49152, tx_qkv_b + l*384,
                                        W + o_qkv, 128, 384, 0, 0);
    attn_kernel<<<256, 256, 0, stream>>>(W + o_qkv, mask, W + o_attn);
    mm_kernel<<<512, 256, 0, stream>>>(W + o_attn, tx_out_w + (size_t)l*16384, tx_out_b + l*128,
                                       W + o_z, 128, 128, 0, 1);
    ln128_kernel<<<256, 256, 0, stream>>>(W + o_z, W + o_y, tx_ln2_g + l*128, tx_ln2_b + l*128, nullptr);
    mm_kernel<<<1024, 256, 0, stream>>>(W + o_y, tx_ff1_w + (size_t)l*32768, tx_ff1_b + l*256,
                                        W + o_ff1, 128, 256, 1, 0);
    mm_kernel<<<512, 256, 0, stream>>>(W + o_ff1, tx_ff2_w + (size_t)l*32768, tx_ff2_b + l*128,
                                       W + o_z, 256, 128, 0, 1);
  }

  // 5. final LN -> ctx (masked)
  ln128_kernel<<<256, 256, 0, stream>>>(W + o_z, W + o_ctx, tx_fln_g, tx_fln_b, mask);

  // 6. router stats
  router_kernel<<<32, 128, 0, stream>>>(W + o_ctx, mask, W + o_meanctx, W + o_router);

  // 7. gates
  gate_kernel<<<1, 64, 0, stream>>>(W + o_router, gate_f_w, gate_f_b, 32, 256,
                                    (int*)(W + o_tif), W + o_twf, W + o_logitsf);
  gate_kernel<<<1, 64, 0, stream>>>(W + o_router, gate_fail_w, gate_fail_b, 32, 256,
                                    (int*)(W + o_tifail), W + o_twfail, nullptr);
  gate_kernel<<<16, 64, 0, stream>>>(W + o_ctx, gate_rca_w, gate_rca_b, 1024, 128,
                                     (int*)(W + o_tirca), W + o_twrca, nullptr);

  // 8. experts
  moe_expert_kernel<<<32, 256, 0, stream>>>(W + o_meanctx, (int*)(W + o_tif), W + o_twf,
                                            exp_w1, exp_b1, exp_w2, exp_b2, nullptr, W + o_moef);
  moe_expert_kernel<<<32, 256, 0, stream>>>(W + o_meanctx, (int*)(W + o_tifail), W + o_twfail,
                                            exp_w1, exp_b1, exp_w2, exp_b2, nullptr, W + o_moefail);
  moe_expert_kernel<<<1024, 256, 0, stream>>>(W + o_ctx, (int*)(W + o_tirca), W + o_twrca,
                                              exp_w1, exp_b1, exp_w2, exp_b2, mask, W + o_moerca);

  // 9. aux loss
  aux_kernel<<<1, 64, 0, stream>>>(W + o_logitsf, (int*)(W + o_tif), out + 4192);

  // 10. heads
  heads_kernel<<<4, 256, 0, stream>>>(W + o_stlast, W + o_ctx, W + o_moef, W + o_moerca,
                                      pred_w, pred_b, rca_w, rca_b, out);
  fail_kernel<<<1, 128, 0, stream>>>(W + o_moefail, fail_w, fail_b, out);
}